// Round 6
// baseline (38.319 us; speedup 1.0000x reference)
//
#include <hip/hip_runtime.h>

#define POOL 7
#define NUM_ROIS 512
#define H_IMG 128
#define W_IMG 128
#define C_IMG 1024
#define NITEMS (NUM_ROIS * POOL)   // 3584 work items = (roi, py) rows

typedef float f32x4 __attribute__((ext_vector_type(4)));

// ---------------------------------------------------------------------------
// Pre-pass: counting-sort the 3584 (roi,py) work items by source image row
// ay0 = y + y0 (128 bins, parallel Hillis-Steele scan). Rewrites perm[]
// entirely every call; within-bin order is atomic-timing dependent but
// harmless (each item writes a disjoint output slice).
// ---------------------------------------------------------------------------
__device__ __forceinline__ int item_key(const int4 roi, int py) {
    const float hf = (float)roi.w;                       // h
    float ysf = ((float)py + 0.5f) * hf / 7.0f - 0.5f;
    ysf = fminf(fmaxf(ysf, 0.0f), hf - 1.0f);
    return roi.y + (int)floorf(ysf);                     // ay0 in [0,127]
}

__global__ __launch_bounds__(1024) void build_perm_kernel(
    const int* __restrict__ rois, int* __restrict__ perm)
{
    __shared__ int hist[128];
    __shared__ int scan[128];
    const int tid = threadIdx.x;
    if (tid < 128) hist[tid] = 0;
    __syncthreads();

    for (int i = tid; i < NITEMS; i += 1024) {
        const int r = i / POOL, py = i - r * POOL;
        const int4 roi = ((const int4*)rois)[r];
        atomicAdd(&hist[item_key(roi, py)], 1);
    }
    __syncthreads();

    if (tid < 128) scan[tid] = hist[tid];
    __syncthreads();
    #pragma unroll
    for (int off = 1; off < 128; off <<= 1) {
        int v = 0;
        if (tid < 128 && tid >= off) v = scan[tid - off];
        __syncthreads();
        if (tid < 128) scan[tid] += v;
        __syncthreads();
    }
    if (tid < 128) hist[tid] = scan[tid] - hist[tid];   // exclusive cursor
    __syncthreads();

    for (int i = tid; i < NITEMS; i += 1024) {
        const int r = i / POOL, py = i - r * POOL;
        const int4 roi = ((const int4*)rois)[r];
        const int pos = atomicAdd(&hist[item_key(roi, py)], 1);
        perm[pos] = i;
    }
}

// ---------------------------------------------------------------------------
// Main kernel. __launch_bounds__(256,3): VGPR cap ~170 so all 28 gather
// results can be live at once; sched_barrier(0) forbids the compiler from
// sinking loads into the blend loop (round-5 showed it does exactly that,
// VGPR=36 => only ~4 loads in flight => latency-bound at 2.1 TB/s).
// ---------------------------------------------------------------------------
__global__ __launch_bounds__(256, 3) void roi_pool_row_kernel(
    const float* __restrict__ img,   // (H, W, C)
    const int*   __restrict__ rois,  // (R, 4) as (x, y, w, h)
    const int*   __restrict__ perm,  // (NITEMS) sorted work ids
    float*       __restrict__ out)   // (R, P, P, C)
{
    const int bid  = blockIdx.x;
    const int swz  = (bid & 7) * (NITEMS / 8) + (bid >> 3);
    const int item = perm[swz];
    const int r    = item / POOL;
    const int py   = item - r * POOL;

    const int4 roi = ((const int4*)rois)[r];
    const int x = roi.x, y = roi.y, w = roi.z, h = roi.w;
    const float hf = (float)h, wf = (float)w;

    // y interpolation (same fp32 expression order as reference)
    float ysf = ((float)py + 0.5f) * hf / 7.0f - 0.5f;
    ysf = fminf(fmaxf(ysf, 0.0f), hf - 1.0f);
    const int   y0 = (int)floorf(ysf);
    const int   y1 = min(y0 + 1, h - 1);
    const float fy = ysf - (float)y0;
    const float gy = 1.0f - fy;

    const f32x4* __restrict__ row0 =
        (const f32x4*)(img + (size_t)(y + y0) * W_IMG * C_IMG);
    const f32x4* __restrict__ row1 =
        (const f32x4*)(img + (size_t)(y + y1) * W_IMG * C_IMG);

    // x interpolation for all 7 px
    int   ax0[POOL], ax1[POOL];
    float fx[POOL];
    #pragma unroll
    for (int px = 0; px < POOL; ++px) {
        float xsf = ((float)px + 0.5f) * wf / 7.0f - 0.5f;
        xsf = fminf(fmaxf(xsf, 0.0f), wf - 1.0f);
        const int x0 = (int)floorf(xsf);
        const int x1 = min(x0 + 1, w - 1);
        fx[px]  = xsf - (float)x0;
        ax0[px] = x + x0;
        ax1[px] = x + x1;
    }

    const int t = threadIdx.x;   // 0..255 ; C/4 == 256 exactly

    // Issue ALL 28 independent loads, then fence against sinking.
    f32x4 A[POOL], B[POOL], C_[POOL], D[POOL];
    #pragma unroll
    for (int px = 0; px < POOL; ++px) {
        A[px]  = row0[(ax0[px] << 8) + t];
        B[px]  = row0[(ax1[px] << 8) + t];
    }
    #pragma unroll
    for (int px = 0; px < POOL; ++px) {
        C_[px] = row1[(ax0[px] << 8) + t];
        D[px]  = row1[(ax1[px] << 8) + t];
    }
    // Hard scheduling fence: no instruction may cross. Keeps all 28
    // global_load_dwordx4 issued before the first blend consumes one.
    __builtin_amdgcn_sched_barrier(0);

    f32x4* __restrict__ po =
        (f32x4*)(out + ((size_t)(r * 49 + py * 7)) * C_IMG);

    #pragma unroll
    for (int px = 0; px < POOL; ++px) {
        const float f = fx[px], g = 1.0f - f;
        f32x4 top = A[px]  * g + B[px] * f;
        f32x4 bot = C_[px] * g + D[px] * f;
        f32x4 o   = top * gy + bot * fy;
        // Output is write-once, never re-read: bypass cache allocation.
        __builtin_nontemporal_store(o, &po[(px << 8) + t]);
    }
}

extern "C" void kernel_launch(void* const* d_in, const int* in_sizes, int n_in,
                              void* d_out, int out_size, void* d_ws, size_t ws_size,
                              hipStream_t stream) {
    const float* img  = (const float*)d_in[0];   // (1,128,128,1024) fp32
    const int*   rois = (const int*)d_in[1];     // (1,512,4) int32
    float*       out  = (float*)d_out;           // (1,512,7,7,1024) fp32
    int*         perm = (int*)d_ws;              // NITEMS ints of scratch

    build_perm_kernel<<<1, 1024, 0, stream>>>(rois, perm);
    roi_pool_row_kernel<<<NITEMS, 256, 0, stream>>>(img, rois, perm, out);
}